// Round 1
// baseline (1211.962 us; speedup 1.0000x reference)
//
#include <hip/hip_runtime.h>
#include <hip/hip_fp16.h>

#define IN_F   8192
#define OUT_F  28672
#define NFP    128
#define NB     32            // B*S rows
#define KQTOT  (IN_F / 4)    // 2048 packed dwords per batch row

#define KC     4             // split-K factor
#define KCHUNK (IN_F / KC)   // 2048 k per block

// ws layout (bytes):
//   q_pk : int  [NB][KQTOT]                       [0, 262144)
//   xs   : float[32]                              [262144, ...)
//   act  : float[32][128]                         [263168, 279552)
//   part : int  [KC][NB][OUT_F] (14,680,064 B)    [524288, ...)
#define WS_QPK  0
#define WS_XS   262144
#define WS_ACT  263168
#define WS_PART 524288

typedef int v4i  __attribute__((ext_vector_type(4)));
typedef int v16i __attribute__((ext_vector_type(16)));

__device__ __forceinline__ int pack8(int4 v) {
    return (v.x & 0xFF) | ((v.y & 0xFF) << 8) | ((v.z & 0xFF) << 16) | (v.w << 24);
}

// ---------------- Kernel A: dynamic quantization (unchanged) ----------------
__global__ __launch_bounds__(256) void quant_kernel(
    const float* __restrict__ x, const int* __restrict__ ind,
    int* __restrict__ q_pk, float* __restrict__ xs_out,
    float* __restrict__ act_out)
{
    __shared__ unsigned char flags[IN_F];   // 8 KB
    __shared__ float redbuf[4];
    __shared__ float xs_sh;
    const int tid = threadIdx.x;
    const int b = blockIdx.x;

    int* fl4 = (int*)flags;
    for (int i = tid; i < IN_F / 4; i += 256) fl4[i] = 0;
    __syncthreads();
    if (tid < NFP) flags[ind[tid]] = 1;
    __syncthreads();

    const float* xrow = x + (size_t)b * IN_F;
    const float4* x4 = (const float4*)xrow;
    float mx = 0.f;
    for (int c = tid; c < IN_F / 4; c += 256) {
        float4 v = x4[c];
        int fw = fl4[c];
        if (!(fw & 0x000000FF)) mx = fmaxf(mx, fabsf(v.x));
        if (!(fw & 0x0000FF00)) mx = fmaxf(mx, fabsf(v.y));
        if (!(fw & 0x00FF0000)) mx = fmaxf(mx, fabsf(v.z));
        if (!(fw & 0xFF000000)) mx = fmaxf(mx, fabsf(v.w));
    }
    #pragma unroll
    for (int off = 32; off > 0; off >>= 1) {
        float o = __shfl_down(mx, off, 64);
        mx = o > mx ? o : mx;
    }
    if ((tid & 63) == 0) redbuf[tid >> 6] = mx;
    __syncthreads();
    if (tid == 0) {
        float m = redbuf[0];
        #pragma unroll
        for (int i = 1; i < 4; i++) m = redbuf[i] > m ? redbuf[i] : m;
        float xs = __half2float(__float2half_rn(m / 127.0f));   // x_scale = f16(max/127)
        xs_sh = xs;
        xs_out[b] = xs;
    }
    __syncthreads();
    const float xs = xs_sh;

    for (int c = tid; c < IN_F / 4; c += 256) {
        float4 v = x4[c];
        int fw = fl4[c];
        float ee[4];
        ee[0] = (fw & 0x000000FF) ? 0.f : v.x;
        ee[1] = (fw & 0x0000FF00) ? 0.f : v.y;
        ee[2] = (fw & 0x00FF0000) ? 0.f : v.z;
        ee[3] = (fw & 0xFF000000) ? 0.f : v.w;
        int pk = 0;
        #pragma unroll
        for (int j = 0; j < 4; j++) {
            float qf = __half2float(__float2half_rn(ee[j] / xs));
            float r = rintf(qf);
            r = fminf(fmaxf(r, -128.f), 127.f);
            int qi = (int)r;
            pk |= (qi & 0xFF) << (8 * j);
        }
        q_pk[(size_t)b * KQTOT + c] = pk;
    }
    if (tid < NFP) act_out[b * NFP + tid] = xrow[ind[tid]];
}

// ---------------- Kernel B: split-K MFMA int8 GEMM, double-buffered ----------------
#define OT    64          // outputs per block (32 per wave, 2 waves)
#define KT    256         // k per tile
#define KQT   (KT / 4)    // 64 packed dwords per row per tile
#define WROW  68          // padded row stride (16B-aligned; 68 % 32 == 4 -> mild conflict)
#define QROW  68
#define NTILE (KCHUNK / KT)   // 8 tiles per block

__device__ __forceinline__ void stage_tiles(
    const int* __restrict__ w, const int* __restrict__ q_pk,
    int* __restrict__ wp, int* __restrict__ qt,
    int tid, int blk_o, int k0)
{
    // W tile: 64 rows x 256 k (int32) -> packed int8, b128 LDS writes.
    // u-map: 16 lanes cover 1 KB contiguous global -> fully coalesced.
    #pragma unroll 4
    for (int i = 0; i < 8; i++) {
        int u  = i * 128 + tid;
        int r  = u >> 4;          // row 0..63
        int c4 = u & 15;          // 4-dword packed chunk 0..15
        const int* src = w + (size_t)(blk_o + r) * IN_F + k0 + c4 * 16;
        int4 a = *(const int4*)(src + 0);
        int4 b = *(const int4*)(src + 4);
        int4 c = *(const int4*)(src + 8);
        int4 d = *(const int4*)(src + 12);
        int4 pk = make_int4(pack8(a), pack8(b), pack8(c), pack8(d));
        *(int4*)&wp[r * WROW + c4 * 4] = pk;
    }
    // q tile: 32 batches x 64 packed dwords (b128 copies)
    #pragma unroll
    for (int i = 0; i < 4; i++) {
        int u  = i * 128 + tid;
        int bb = u >> 4;          // batch 0..31
        int c4 = u & 15;
        int4 v = *(const int4*)(q_pk + (size_t)bb * KQTOT + (k0 >> 2) + c4 * 4);
        *(int4*)&qt[bb * QROW + c4 * 4] = v;
    }
}

__global__ __launch_bounds__(128) void gemm_kernel(
    const int* __restrict__ w, const int* __restrict__ q_pk,
    int* __restrict__ part)
{
    __shared__ int w_p[2][OT * WROW] __attribute__((aligned(16)));   // 2 x 17408 B
    __shared__ int q_t[2][NB * QROW] __attribute__((aligned(16)));   // 2 x  8704 B

    const int tid  = threadIdx.x;
    const int wave = tid >> 6;
    const int lane = tid & 63;
    const int nl   = lane & 31;     // output column within wave tile
    const int half = lane >> 5;     // k-half selector for A/B fragments

    const int kc    = blockIdx.x & (KC - 1);
    const int blk_o = (blockIdx.x >> 2) * OT;
    const int kbase = kc * KCHUNK;
    const int n = blk_o + wave * 32 + nl;

    v16i acc;
    #pragma unroll
    for (int r = 0; r < 16; r++) acc[r] = 0;

    // prologue: stage tile 0 into buffer 0
    stage_tiles(w, q_pk, w_p[0], q_t[0], tid, blk_o, kbase);
    __syncthreads();

    for (int t = 0; t < NTILE; ++t) {
        const int cur = t & 1;
        // issue next tile's loads BEFORE the MFMAs -> VMEM overlaps compute
        if (t + 1 < NTILE)
            stage_tiles(w, q_pk, w_p[cur ^ 1], q_t[cur ^ 1],
                        tid, blk_o, kbase + (t + 1) * KT);

        const int* qrow = &q_t[cur][nl * QROW + half * 4];
        const int* wrow = &w_p[cur][(wave * 32 + nl) * WROW + half * 4];
        #pragma unroll
        for (int s = 0; s < KT / 32; s++) {
            v4i a = *(const v4i*)(qrow + s * 8);   // ds_read_b128
            v4i b = *(const v4i*)(wrow + s * 8);   // ds_read_b128
            acc = __builtin_amdgcn_mfma_i32_32x32x32_i8(a, b, acc, 0, 0, 0);
        }
        __syncthreads();   // one barrier per tile: buf^1 staged, buf^cur reads done
    }

    // int32 partials (exact); epilogue kernel reduces across kc
    #pragma unroll
    for (int r = 0; r < 16; r++) {
        int b = (r & 3) + 8 * (r >> 2) + 4 * half;   // C/D row = batch
        part[((size_t)kc * NB + b) * OUT_F + n] = acc[r];
    }
}

// ---------------- Kernel C: reduce partials + f32 epilogue ----------------
__global__ __launch_bounds__(256) void epilogue_kernel(
    const int* __restrict__ part, const float* __restrict__ xs_ws,
    const float* __restrict__ act_ws, const float* __restrict__ sc,
    const float* __restrict__ wc, const float* __restrict__ bias,
    float* __restrict__ out)
{
    __shared__ float act_l[NB * NFP];   // 16 KB
    __shared__ float xs_l[NB];
    const int tid = threadIdx.x;
    const int blk_o = blockIdx.x * 64;

    for (int i = tid; i < NB * NFP; i += 256) act_l[i] = act_ws[i];
    if (tid < NB) xs_l[tid] = xs_ws[tid];
    __syncthreads();

    const int nl = tid & 63;
    const int n  = blk_o + nl;
    const int b0 = (tid >> 6) * 8;      // each thread: 8 batches x 1 output
    const float scn = sc[n];
    const float bin = bias[n];
    const float* wcn = wc + (size_t)n * NFP;

    float dots[8];
    #pragma unroll
    for (int j = 0; j < 8; j++) dots[j] = 0.f;
    for (int u = 0; u < NFP; u += 4) {
        float4 wv = *(const float4*)(wcn + u);
        #pragma unroll
        for (int j = 0; j < 8; j++) {
            float4 av = *(const float4*)(&act_l[(b0 + j) * NFP + u]);  // LDS broadcast
            dots[j] += av.x * wv.x + av.y * wv.y + av.z * wv.z + av.w * wv.w;
        }
    }

    #pragma unroll
    for (int j = 0; j < 8; j++) {
        const int b = b0 + j;
        const size_t idx = (size_t)b * OUT_F + n;
        int s = part[idx];
        #pragma unroll
        for (int k = 1; k < KC; k++) s += part[((size_t)k * NB + b) * OUT_F + n];
        out[idx] = (float)s * xs_l[b] * scn + dots[j] + bin;
    }
}

extern "C" void kernel_launch(void* const* d_in, const int* in_sizes, int n_in,
                              void* d_out, int out_size, void* d_ws, size_t ws_size,
                              hipStream_t stream) {
    const float* x    = (const float*)d_in[0];
    const int*   wgt  = (const int*)d_in[1];
    const float* scol = (const float*)d_in[2];
    const float* wch  = (const float*)d_in[3];
    const float* bias = (const float*)d_in[4];
    const int*   ind  = (const int*)d_in[5];
    float* out = (float*)d_out;

    int*   q_pk = (int*)((char*)d_ws + WS_QPK);
    float* xs   = (float*)((char*)d_ws + WS_XS);
    float* act  = (float*)((char*)d_ws + WS_ACT);
    int*   part = (int*)((char*)d_ws + WS_PART);

    quant_kernel<<<NB, 256, 0, stream>>>(x, ind, q_pk, xs, act);
    gemm_kernel<<<(OUT_F / OT) * KC, 128, 0, stream>>>(wgt, q_pk, part);
    epilogue_kernel<<<OUT_F / 64, 256, 0, stream>>>(part, xs, act, scol, wch, bias, out);
}